// Round 9
// baseline (113.062 us; speedup 1.0000x reference)
//
#include <hip/hip_runtime.h>
#include <hip/hip_bf16.h>
#include <stdint.h>

#define N_TOT 8192
#define BHALF 4096
#define DIM   256
#define E2     7.38905609893065f    // exp(2): diag term, subtracted in fin
#define LOG2E2 2.8853900817779268f  // 2*log2(e): exp(2x) = exp2(x*LOG2E2)

typedef short s8v __attribute__((ext_vector_type(8)));   // 8 bf16 in 4 VGPRs
typedef float f4v __attribute__((ext_vector_type(4)));   // MFMA accumulator

static __device__ __forceinline__ unsigned short f2bf(float f) {
    union { float f; uint32_t u; } v; v.f = f;
    uint32_t r = (v.u + 0x7FFFu + ((v.u >> 16) & 1u)) >> 16;  // RNE
    return (unsigned short)r;
}

// Fragment-major layout: granule g = (row>>4)*8 + (k8>>2), lane = (row&15) + 16*(k8&3),
// k8 = k/8. One granule (2KB) = one wave MFMA fragment (16 rows x 32 k), lane-ordered
// => every A/B fragment load is a single contiguous 1KB coalesced wave-load.

// K1: normalize pair rows (p from z_i, p+4096 from z_j), emit fragment-major bf16,
// label sims in fp32, zero sumexp slice.
__global__ __launch_bounds__(256) void nrm_kernel(const float* __restrict__ zi,
                                                  const float* __restrict__ zj,
                                                  s8v* __restrict__ zbF,
                                                  float* __restrict__ sumexp,
                                                  float* __restrict__ lab2) {
    const int wave = threadIdx.x >> 6;
    const int lane = threadIdx.x & 63;
    const int half = lane >> 5;          // 0: row p, 1: row p+4096
    const int sl   = lane & 31;          // k8 chunk (8 elems)
    const int p    = blockIdx.x * 4 + wave;
    const int row  = half ? (p + BHALF) : p;
    const float* src = (half ? zj : zi) + (size_t)p * DIM;

    float4 v0 = *(const float4*)(src + sl * 8);
    float4 v1 = *(const float4*)(src + sl * 8 + 4);
    float s = v0.x*v0.x + v0.y*v0.y + v0.z*v0.z + v0.w*v0.w
            + v1.x*v1.x + v1.y*v1.y + v1.z*v1.z + v1.w*v1.w;
    #pragma unroll
    for (int m = 1; m < 32; m <<= 1) s += __shfl_xor(s, m, 64);  // within half
    const float inv = 1.0f / fmaxf(sqrtf(s), 1e-12f);

    float n[8] = { v0.x*inv, v0.y*inv, v0.z*inv, v0.w*inv,
                   v1.x*inv, v1.y*inv, v1.z*inv, v1.w*inv };
    union { s8v v; unsigned short u[8]; } o;
    #pragma unroll
    for (int j = 0; j < 8; ++j) o.u[j] = f2bf(n[j]);
    zbF[(size_t)(((row >> 4) * 8 + (sl >> 2)) * 64) + (row & 15) + 16 * (sl & 3)] = o.v;

    float d = 0.f;
    #pragma unroll
    for (int j = 0; j < 8; ++j) d += n[j] * __shfl_xor(n[j], 32, 64);
    #pragma unroll
    for (int m = 1; m < 32; m <<= 1) d += __shfl_xor(d, m, 64);
    if (lane == 0) lab2[p] = 2.0f * d;

    if (threadIdx.x < 8) sumexp[blockIdx.x * 8 + threadIdx.x] = 0.f;
}

// K2: sim + exp-sum over the UPPER TRIANGLE of 256x256 tiles only (sim is exactly
// symmetric: row-frag i and col-frag i are the same granules). Off-diagonal tiles
// contribute row-sums AND column-sums; diagonal tiles row-sums only.
// Grid 1024 = 32x32 tiles; lower-triangle blocks exit (528 live).
__global__ __launch_bounds__(256, 2) void sim_kernel(const s8v* __restrict__ zbF,
                                                     float* __restrict__ sumexp) {
    const int rb = blockIdx.x >> 5;
    const int cb = blockIdx.x & 31;
    if (cb < rb) return;                 // symmetry: skip lower triangle
    const int lane = threadIdx.x & 63;
    const int wave = threadIdx.x >> 6;
    const int row0 = rb * 256 + wave * 64;
    const int ct0  = cb * 16;            // col-tile base (16-col units)
    const int l15  = lane & 15;
    const int quad = lane >> 4;
    const bool offdiag = (rb != cb);

    // A fragments: 4 row-tiles x 8 k-chunks, each one contiguous granule. 128 VGPRs.
    s8v a[4][8];
    #pragma unroll
    for (int rt = 0; rt < 4; ++rt) {
        const s8v* ap = zbF + (size_t)(((row0 >> 4) + rt) * 8) * 64 + lane;
        #pragma unroll
        for (int c = 0; c < 8; ++c) a[rt][c] = ap[c * 64];
    }
    // Pin A in VGPRs (R2's VGPR=100 proved the compiler re-loads otherwise).
    #pragma unroll
    for (int rt = 0; rt < 4; ++rt)
        #pragma unroll
        for (int c = 0; c < 8; ++c)
            asm volatile("" : "+v"(a[rt][c]));

    float se[4][4];
    #pragma unroll
    for (int rt = 0; rt < 4; ++rt)
        #pragma unroll
        for (int r = 0; r < 4; ++r) se[rt][r] = 0.f;

    s8v b0[8], b1[8];
    {
        const s8v* bp = zbF + (size_t)(ct0 * 8) * 64 + lane;
        #pragma unroll
        for (int c = 0; c < 8; ++c) b0[c] = bp[c * 64];
    }

#define SIM_BODY(BCUR, BNXT, CT)                                                   \
    {                                                                              \
        const s8v* np = zbF + (size_t)((ct0 + (((CT) + 1) & 15)) * 8) * 64 + lane; \
        _Pragma("unroll")                                                          \
        for (int c = 0; c < 8; ++c) BNXT[c] = np[c * 64];                          \
        f4v acc[4];                                                                \
        _Pragma("unroll")                                                          \
        for (int rt = 0; rt < 4; ++rt) acc[rt] = (f4v){0.f, 0.f, 0.f, 0.f};       \
        _Pragma("unroll")                                                          \
        for (int c = 0; c < 8; ++c) {                                              \
            _Pragma("unroll")                                                      \
            for (int rt = 0; rt < 4; ++rt)                                         \
                acc[rt] = __builtin_amdgcn_mfma_f32_16x16x32_bf16(                 \
                    a[rt][c], BCUR[c], acc[rt], 0, 0, 0);                          \
        }                                                                          \
        float cl = 0.f;                                                            \
        _Pragma("unroll")                                                          \
        for (int rt = 0; rt < 4; ++rt)                                             \
            _Pragma("unroll")                                                      \
            for (int r = 0; r < 4; ++r) {                                          \
                const float e = __builtin_amdgcn_exp2f(acc[rt][r] * LOG2E2);       \
                se[rt][r] += e;                                                    \
                cl += e;                                                           \
            }                                                                      \
        if (offdiag) {                                                             \
            cl += __shfl_xor(cl, 16, 64);                                          \
            cl += __shfl_xor(cl, 32, 64);                                          \
            if (quad == 0)                                                         \
                atomicAdd(&sumexp[(ct0 + (CT)) * 16 + l15], cl);                   \
        }                                                                          \
    }

    #pragma unroll 1
    for (int ct = 0; ct < 16; ct += 2) {
        SIM_BODY(b0, b1, ct)
        SIM_BODY(b1, b0, ct + 1)
    }
#undef SIM_BODY

    // row-sums: reduce over the 16 lanes of each quad (same rows, different cols)
    #pragma unroll
    for (int rt = 0; rt < 4; ++rt) {
        #pragma unroll
        for (int r = 0; r < 4; ++r) {
            float s = se[rt][r];
            #pragma unroll
            for (int m = 1; m < 16; m <<= 1) s += __shfl_xor(s, m, 64);
            if (l15 == 0)
                atomicAdd(&sumexp[row0 + rt*16 + quad*4 + r], s);
        }
    }
}

// K3: loss = mean_i( log(sumexp_i - e^2) ) - mean_i( sim_{i,label} )
__global__ __launch_bounds__(256) void fin_kernel(const float* __restrict__ sumexp,
                                                  const float* __restrict__ lab2,
                                                  float* __restrict__ out) {
    const int tid = threadIdx.x;
    float acc = 0.f;
    for (int i = tid; i < N_TOT; i += 256)
        acc += logf(sumexp[i] - E2);
    for (int p = tid; p < BHALF; p += 256)
        acc -= 2.0f * lab2[p];
    #pragma unroll
    for (int m = 1; m < 64; m <<= 1) acc += __shfl_xor(acc, m, 64);
    __shared__ float wsum[4];
    if ((tid & 63) == 0) wsum[tid >> 6] = acc;
    __syncthreads();
    if (tid == 0) out[0] = (wsum[0] + wsum[1] + wsum[2] + wsum[3]) / (float)N_TOT;
}

extern "C" void kernel_launch(void* const* d_in, const int* in_sizes, int n_in,
                              void* d_out, int out_size, void* d_ws, size_t ws_size,
                              hipStream_t stream) {
    const float* zi = (const float*)d_in[0];
    const float* zj = (const float*)d_in[1];
    s8v* zbF = (s8v*)d_ws;                                             // 4 MB bf16
    float* sumexp = (float*)((char*)d_ws + (size_t)N_TOT * DIM * 2);   // 32 KB
    float* lab2   = sumexp + N_TOT;                                    // 16 KB

    nrm_kernel<<<1024, 256, 0, stream>>>(zi, zj, zbF, sumexp, lab2);
    sim_kernel<<<1024, 256, 0, stream>>>(zbF, sumexp);
    fin_kernel<<<1, 256, 0, stream>>>(sumexp, lab2, (float*)d_out);
}